// Round 5
// baseline (1102.255 us; speedup 1.0000x reference)
//
#include <hip/hip_runtime.h>

typedef unsigned short u16;
typedef unsigned int u32;
typedef __bf16 bf16x8 __attribute__((ext_vector_type(8)));
typedef float f32x4 __attribute__((ext_vector_type(4)));

#define M_TOK 8192
#define DMODEL 768
#define DINNER 1536
#define NSTATE 16
#define DTRANK 48
#define SEQLEN 2048

__device__ __forceinline__ float bf2f(u16 v) {
    return __builtin_bit_cast(float, (u32)v << 16);
}
__device__ __forceinline__ u16 f2bf(float f) {
    u32 u = __builtin_bit_cast(u32, f);
    return (u16)((u + 0x7FFFu + ((u >> 16) & 1u)) >> 16);
}

// ---------------- fp32 -> bf16 converter (n % 4 == 0) ----------------
__global__ __launch_bounds__(256) void cvt_kernel(
    const float* __restrict__ src, u16* __restrict__ dst, int n4)
{
    int i = blockIdx.x * 256 + threadIdx.x;
    if (i >= n4) return;
    float4 v = ((const float4*)src)[i];
    ushort4 o;
    o.x = f2bf(v.x); o.y = f2bf(v.y); o.z = f2bf(v.z); o.w = f2bf(v.w);
    ((ushort4*)dst)[i] = o;
}

// ---------------- fused residual add + layernorm (fp32 in, fp32 res_out, bf16 u) ----------------
__global__ __launch_bounds__(256) void ln_kernel(
    const float* __restrict__ x, const float* __restrict__ res,
    const float* __restrict__ g, const float* __restrict__ b,
    float* __restrict__ res_out, u16* __restrict__ u)
{
    __shared__ float sbuf[4];
    const int row = blockIdx.x;
    const int tid = threadIdx.x;
    const size_t base = (size_t)row * DMODEL;
    float v[3];
    float s = 0.f;
#pragma unroll
    for (int i = 0; i < 3; i++) {
        int idx = tid + i * 256;
        v[i] = x[base + idx] + res[base + idx];
        res_out[base + idx] = v[i];
        s += v[i];
    }
#pragma unroll
    for (int o = 1; o < 64; o <<= 1) s += __shfl_xor(s, o);
    if ((tid & 63) == 0) sbuf[tid >> 6] = s;
    __syncthreads();
    s = sbuf[0] + sbuf[1] + sbuf[2] + sbuf[3];
    const float mean = s * (1.f / 768.f);
    float var = 0.f;
#pragma unroll
    for (int i = 0; i < 3; i++) { float d = v[i] - mean; var += d * d; }
#pragma unroll
    for (int o = 1; o < 64; o <<= 1) var += __shfl_xor(var, o);
    __syncthreads();
    if ((tid & 63) == 0) sbuf[tid >> 6] = var;
    __syncthreads();
    var = (sbuf[0] + sbuf[1] + sbuf[2] + sbuf[3]) * (1.f / 768.f);
    const float rs = rsqrtf(var + 1e-5f);
#pragma unroll
    for (int i = 0; i < 3; i++) {
        int idx = tid + i * 256;
        u[base + idx] = f2bf((v[i] - mean) * rs * g[idx] + b[idx]);
    }
}

// ---------------- big GEMM: C[M,N] = A[M,K]*B[N,K]^T, bf16 in, bf16 or fp32 out ----------------
template<bool F32OUT>
__global__ __launch_bounds__(256) void gemm_bt(
    const u16* __restrict__ A, int lda, const u16* __restrict__ B, int ldb,
    void* __restrict__ Cv, int ldc, int K)
{
    __shared__ uint4 As[512];   // 128 rows x 4 uint4 (32 bf16/row)
    __shared__ uint4 Bs[512];
    const int tid = threadIdx.x;
    const int wid = tid >> 6;
    const int lane = tid & 63;
    const int m0 = blockIdx.y * 128;
    const int n0 = blockIdx.x * 128;
    const int wm = (wid >> 1) * 64;
    const int wn = (wid & 1) * 64;
    f32x4 acc[4][4];
#pragma unroll
    for (int i = 0; i < 4; i++)
#pragma unroll
        for (int j = 0; j < 4; j++) acc[i][j] = (f32x4){0.f, 0.f, 0.f, 0.f};

    const int r0 = tid >> 2;     // staging row 0..63
    const int cq = tid & 3;      // uint4 column 0..3
    const uint4* pa0 = (const uint4*)(A + (size_t)(m0 + r0) * lda) + cq;
    const uint4* pa1 = (const uint4*)(A + (size_t)(m0 + 64 + r0) * lda) + cq;
    const uint4* pb0 = (const uint4*)(B + (size_t)(n0 + r0) * ldb) + cq;
    const uint4* pb1 = (const uint4*)(B + (size_t)(n0 + 64 + r0) * ldb) + cq;
    const int fr = lane & 15;    // fragment row (m or n)
    const int kq = lane >> 4;    // fragment k-block (uint4 index)

    for (int k0 = 0; k0 < K; k0 += 32) {
        const int kk = k0 >> 3;  // uint4 step
        uint4 a0 = pa0[kk];
        uint4 a1 = pa1[kk];
        uint4 b0 = pb0[kk];
        uint4 b1 = pb1[kk];
        __syncthreads();         // prior iteration's fragment reads done
        As[r0 * 4 + cq] = a0;
        As[(64 + r0) * 4 + cq] = a1;
        Bs[r0 * 4 + cq] = b0;
        Bs[(64 + r0) * 4 + cq] = b1;
        __syncthreads();
        bf16x8 af[4], bfr[4];
#pragma unroll
        for (int i = 0; i < 4; i++) {
            af[i]  = __builtin_bit_cast(bf16x8, As[(wm + i * 16 + fr) * 4 + kq]);
            bfr[i] = __builtin_bit_cast(bf16x8, Bs[(wn + i * 16 + fr) * 4 + kq]);
        }
#pragma unroll
        for (int i = 0; i < 4; i++)
#pragma unroll
            for (int j = 0; j < 4; j++)
                acc[i][j] = __builtin_amdgcn_mfma_f32_16x16x32_bf16(af[i], bfr[j], acc[i][j], 0, 0, 0);
    }
    const int col = lane & 15;
    const int rb = (lane >> 4) * 4;
#pragma unroll
    for (int i = 0; i < 4; i++)
#pragma unroll
        for (int j = 0; j < 4; j++)
#pragma unroll
            for (int r = 0; r < 4; r++) {
                int m = m0 + wm + i * 16 + rb + r;
                int nn = n0 + wn + j * 16 + col;
                if (F32OUT)
                    ((float*)Cv)[(size_t)m * ldc + nn] = acc[i][j][r];
                else
                    ((u16*)Cv)[(size_t)m * ldc + nn] = f2bf(acc[i][j][r]);
            }
}

// ---------------- flexible small GEMM (K zero-padded), bf16 in/out, fp32 bias ----------------
template<int TM, int TN, int EPI>
__global__ __launch_bounds__(256) void gemm_bt_flex(
    const u16* __restrict__ A, int lda, const u16* __restrict__ B, int ldb,
    const float* __restrict__ bias, u16* __restrict__ C, int ldc, int K)
{
    constexpr int BM = 64 * TM;
    constexpr int BN = 16 * TN;
    __shared__ __align__(16) u32 As32[BM * 16];   // row = 16 u32 = 32 bf16
    __shared__ __align__(16) u32 Bs32[BN * 16];
    const int tid = threadIdx.x;
    const int wid = tid >> 6;
    const int lane = tid & 63;
    const int m0 = blockIdx.y * BM;
    const int n0 = blockIdx.x * BN;
    f32x4 acc[TM][TN];
#pragma unroll
    for (int i = 0; i < TM; i++)
#pragma unroll
        for (int j = 0; j < TN; j++) acc[i][j] = (f32x4){0.f, 0.f, 0.f, 0.f};
    const int fr = lane & 15;
    const int kq = lane >> 4;       // u32 offset = kq*4 within row
    const int ksteps = (K + 31) >> 5;

    for (int kt = 0; kt < ksteps; kt++) {
        const int k0 = kt * 32;
        __syncthreads();
        for (int e = tid; e < BM * 16; e += 256) {
            int r = e >> 4, c2 = (e & 15) * 2;
            int k = k0 + c2;
            u32 lo = (k < K)     ? (u32)A[(size_t)(m0 + r) * lda + k]     : 0u;
            u32 hi = (k + 1 < K) ? (u32)A[(size_t)(m0 + r) * lda + k + 1] : 0u;
            As32[e] = lo | (hi << 16);
        }
        for (int e = tid; e < BN * 16; e += 256) {
            int r = e >> 4, c2 = (e & 15) * 2;
            int k = k0 + c2;
            u32 lo = (k < K)     ? (u32)B[(size_t)(n0 + r) * ldb + k]     : 0u;
            u32 hi = (k + 1 < K) ? (u32)B[(size_t)(n0 + r) * ldb + k + 1] : 0u;
            Bs32[e] = lo | (hi << 16);
        }
        __syncthreads();
        bf16x8 af[TM], bfr[TN];
#pragma unroll
        for (int i = 0; i < TM; i++) {
            uint4 t4;
            __builtin_memcpy(&t4, &As32[(wid * 16 * TM + i * 16 + fr) * 16 + kq * 4], 16);
            af[i] = __builtin_bit_cast(bf16x8, t4);
        }
#pragma unroll
        for (int j = 0; j < TN; j++) {
            uint4 t4;
            __builtin_memcpy(&t4, &Bs32[(j * 16 + fr) * 16 + kq * 4], 16);
            bfr[j] = __builtin_bit_cast(bf16x8, t4);
        }
#pragma unroll
        for (int i = 0; i < TM; i++)
#pragma unroll
            for (int j = 0; j < TN; j++)
                acc[i][j] = __builtin_amdgcn_mfma_f32_16x16x32_bf16(af[i], bfr[j], acc[i][j], 0, 0, 0);
    }
    const int col = lane & 15;
    const int rb = (lane >> 4) * 4;
#pragma unroll
    for (int i = 0; i < TM; i++)
#pragma unroll
        for (int j = 0; j < TN; j++)
#pragma unroll
            for (int r = 0; r < 4; r++) {
                int m = m0 + wid * 16 * TM + i * 16 + rb + r;
                int nn = n0 + j * 16 + col;
                float v = acc[i][j][r];
                if (EPI == 1) {
                    v += bias[nn];
                    v = (v > 20.f) ? v : log1pf(__expf(v));  // softplus
                }
                C[(size_t)m * ldc + nn] = f2bf(v);
            }
}

// ---------------- causal depthwise conv(4) + SiLU (bf16 data, fp32 params) ----------------
__global__ __launch_bounds__(256) void conv_silu_kernel(
    const u16* __restrict__ xz, const float* __restrict__ cw, const float* __restrict__ cb,
    u16* __restrict__ xc)
{
    size_t i = (size_t)blockIdx.x * 256 + threadIdx.x;
    if (i >= (size_t)M_TOK * DINNER) return;
    int d = (int)(i % DINNER);
    size_t m = i / DINNER;
    int l = (int)(m & (SEQLEN - 1));
    float acc = cb[d];
#pragma unroll
    for (int k = 0; k < 4; k++) {
        int ls = l - 3 + k;
        if (ls >= 0)
            acc += bf2f(xz[(m - 3 + k) * (2 * DINNER) + d]) * cw[d * 4 + k];
    }
    xc[i] = f2bf(acc / (1.f + __expf(-acc)));
}

// ---------------- selective scan; y written into dead xs-half of xz ----------------
__global__ __launch_bounds__(128) void scan_kernel(
    const u16* __restrict__ dtp, const u16* __restrict__ xc, const u16* __restrict__ proj,
    u16* xz, const float* __restrict__ Alog, const float* __restrict__ Dp)
{
    const int tid = threadIdx.x;
    const int n = tid & 15;
    const int dl = tid >> 4;
    const int b = blockIdx.y;
    const int d = blockIdx.x * 8 + dl;
    const float A_dn = -__expf(Alog[d * NSTATE + n]);
    const float D_d = Dp[d];
    float h = 0.f;
    const size_t tb = (size_t)b * SEQLEN;
    for (int l0 = 0; l0 < SEQLEN; l0 += 8) {
        float vdt[8], vx[8], vB[8], vC[8], vz[8];
#pragma unroll
        for (int q = 0; q < 8; q++) {
            size_t t = tb + l0 + q;
            size_t id = t * DINNER + d;
            vdt[q] = bf2f(dtp[id]);
            vx[q]  = bf2f(xc[id]);
            vB[q]  = bf2f(proj[t * 80 + 48 + n]);
            vC[q]  = bf2f(proj[t * 80 + 64 + n]);
            vz[q]  = bf2f(xz[t * (2 * DINNER) + DINNER + d]);
        }
#pragma unroll
        for (int q = 0; q < 8; q++) {
            float dA = __expf(vdt[q] * A_dn);
            h = fmaf(dA, h, vdt[q] * vx[q] * vB[q]);
            float p = h * vC[q];
            p += __shfl_xor(p, 1, 16);
            p += __shfl_xor(p, 2, 16);
            p += __shfl_xor(p, 4, 16);
            p += __shfl_xor(p, 8, 16);
            if (n == 0) {
                float zv = vz[q];
                float yv = (p + vx[q] * D_d) * (zv / (1.f + __expf(-zv)));
                xz[(tb + l0 + q) * (2 * DINNER) + d] = f2bf(yv);  // y -> dead xs slot
            }
        }
    }
}

extern "C" void kernel_launch(void* const* d_in, const int* in_sizes, int n_in,
                              void* d_out, int out_size, void* d_ws, size_t ws_size,
                              hipStream_t stream) {
    (void)in_sizes; (void)n_in; (void)out_size; (void)ws_size;
    const float* x    = (const float*)d_in[0];
    const float* res  = (const float*)d_in[1];
    const float* lng  = (const float*)d_in[2];
    const float* lnb  = (const float*)d_in[3];
    const float* Win  = (const float*)d_in[4];
    const float* cw   = (const float*)d_in[5];
    const float* cb   = (const float*)d_in[6];
    const float* Wxp  = (const float*)d_in[7];
    const float* Wdt  = (const float*)d_in[8];
    const float* bdt  = (const float*)d_in[9];
    const float* Alog = (const float*)d_in[10];
    const float* Dp   = (const float*)d_in[11];
    const float* Wout = (const float*)d_in[12];

    float* out = (float*)d_out;                      // output 0: (B,L,DMODEL) fp32
    float* res_out = out + (size_t)M_TOK * DMODEL;   // output 1: res+x, fp32

    char* ws = (char*)d_ws;
    u16* xz_buf = (u16*)(ws);                  // 50,331,648 B
    u16* xc_buf = (u16*)(ws + 50331648);       // 25,165,824 B
    u16* dt_buf = (u16*)(ws + 75497472);       // 25,165,824 B
    u16* u_buf  = dt_buf;                      // disjoint lifetime with dt
    u16* pj_buf = (u16*)(ws + 100663296);      //  1,310,720 B
    u16* Winb   = (u16*)(ws + 101974016);      //  4,718,592 B
    u16* Woutb  = (u16*)(ws + 106692608);      //  2,359,296 B
    u16* Wxpb   = (u16*)(ws + 109051904);      //    245,760 B
    u16* Wdtb   = (u16*)(ws + 109297664);      //    147,456 B  (end ~109.4 MB)

    // 0. convert weight matrices fp32 -> bf16
    cvt_kernel<<<(3072 * 768 / 4 + 255) / 256, 256, 0, stream>>>(Win, Winb, 3072 * 768 / 4);
    cvt_kernel<<<(768 * 1536 / 4 + 255) / 256, 256, 0, stream>>>(Wout, Woutb, 768 * 1536 / 4);
    cvt_kernel<<<(80 * 1536 / 4 + 255) / 256, 256, 0, stream>>>(Wxp, Wxpb, 80 * 1536 / 4);
    cvt_kernel<<<(1536 * 48 / 4 + 255) / 256, 256, 0, stream>>>(Wdt, Wdtb, 1536 * 48 / 4);
    // 1. res+x (fp32 out), layernorm (bf16 u)
    ln_kernel<<<M_TOK, 256, 0, stream>>>(x, res, lng, lnb, res_out, u_buf);
    // 2. in_proj: xz = u @ W_in^T  (8192 x 3072, K=768), bf16 out
    gemm_bt<false><<<dim3(3072 / 128, M_TOK / 128), 256, 0, stream>>>(
        u_buf, DMODEL, Winb, DMODEL, xz_buf, 2 * DINNER, DMODEL);
    // 3. conv + silu -> xc
    conv_silu_kernel<<<(M_TOK * DINNER) / 256, 256, 0, stream>>>(xz_buf, cw, cb, xc_buf);
    // 4. x_proj: proj = xc @ W_xproj^T  (8192 x 80, K=1536)
    gemm_bt_flex<1, 5, 0><<<dim3(1, M_TOK / 64), 256, 0, stream>>>(
        xc_buf, DINNER, Wxpb, DINNER, (const float*)nullptr, pj_buf, 80, DINNER);
    // 5. dt = softplus(proj[:, :48] @ W_dt^T + b_dt)  (8192 x 1536, K=48)
    gemm_bt_flex<1, 8, 1><<<dim3(DINNER / 128, M_TOK / 64), 256, 0, stream>>>(
        pj_buf, 80, Wdtb, DTRANK, bdt, dt_buf, DINNER, DTRANK);
    // 6. selective scan -> y into xs-half of xz (fused +xc*D and *silu(z))
    scan_kernel<<<dim3(DINNER / 8, 4), 128, 0, stream>>>(
        dt_buf, xc_buf, pj_buf, xz_buf, Alog, Dp);
    // 7. out_proj: out = y @ W_out^T  (8192 x 768, K=1536), fp32 out
    gemm_bt<true><<<dim3(DMODEL / 128, M_TOK / 128), 256, 0, stream>>>(
        xz_buf, 2 * DINNER, Woutb, DINNER, out, DMODEL, DINNER);
}

// Round 6
// 601.754 us; speedup vs baseline: 1.8317x; 1.8317x over previous
//
#include <hip/hip_runtime.h>

typedef unsigned short u16;
typedef unsigned int u32;
typedef __bf16 bf16x8 __attribute__((ext_vector_type(8)));
typedef float f32x4 __attribute__((ext_vector_type(4)));

#define M_TOK 8192
#define DMODEL 768
#define DINNER 1536
#define NSTATE 16
#define DTRANK 48
#define SEQLEN 2048
#define NCHUNK 32
#define CLEN 64          // SEQLEN / NCHUNK

__device__ __forceinline__ float bf2f(u16 v) {
    return __builtin_bit_cast(float, (u32)v << 16);
}
__device__ __forceinline__ u16 f2bf(float f) {
    u32 u = __builtin_bit_cast(u32, f);
    return (u16)((u + 0x7FFFu + ((u >> 16) & 1u)) >> 16);
}
__device__ __forceinline__ void unpack8(uint4 q, float* f) {
    u32 w[4] = {q.x, q.y, q.z, q.w};
#pragma unroll
    for (int i = 0; i < 4; i++) {
        f[2 * i]     = bf2f((u16)(w[i] & 0xffffu));
        f[2 * i + 1] = bf2f((u16)(w[i] >> 16));
    }
}
__device__ __forceinline__ uint4 pack8(const float* f) {
    uint4 q;
    q.x = (u32)f2bf(f[0]) | ((u32)f2bf(f[1]) << 16);
    q.y = (u32)f2bf(f[2]) | ((u32)f2bf(f[3]) << 16);
    q.z = (u32)f2bf(f[4]) | ((u32)f2bf(f[5]) << 16);
    q.w = (u32)f2bf(f[6]) | ((u32)f2bf(f[7]) << 16);
    return q;
}

// ---------------- fp32 -> bf16 converter (n % 4 == 0) ----------------
__global__ __launch_bounds__(256) void cvt_kernel(
    const float* __restrict__ src, u16* __restrict__ dst, int n4)
{
    int i = blockIdx.x * 256 + threadIdx.x;
    if (i >= n4) return;
    float4 v = ((const float4*)src)[i];
    ushort4 o;
    o.x = f2bf(v.x); o.y = f2bf(v.y); o.z = f2bf(v.z); o.w = f2bf(v.w);
    ((ushort4*)dst)[i] = o;
}

// ---------------- fused residual add + layernorm (fp32 in, fp32 res_out, bf16 u) ----------------
__global__ __launch_bounds__(256) void ln_kernel(
    const float* __restrict__ x, const float* __restrict__ res,
    const float* __restrict__ g, const float* __restrict__ b,
    float* __restrict__ res_out, u16* __restrict__ u)
{
    __shared__ float sbuf[4];
    const int row = blockIdx.x;
    const int tid = threadIdx.x;
    const size_t base = (size_t)row * DMODEL;
    float v[3];
    float s = 0.f;
#pragma unroll
    for (int i = 0; i < 3; i++) {
        int idx = tid + i * 256;
        v[i] = x[base + idx] + res[base + idx];
        res_out[base + idx] = v[i];
        s += v[i];
    }
#pragma unroll
    for (int o = 1; o < 64; o <<= 1) s += __shfl_xor(s, o);
    if ((tid & 63) == 0) sbuf[tid >> 6] = s;
    __syncthreads();
    s = sbuf[0] + sbuf[1] + sbuf[2] + sbuf[3];
    const float mean = s * (1.f / 768.f);
    float var = 0.f;
#pragma unroll
    for (int i = 0; i < 3; i++) { float d = v[i] - mean; var += d * d; }
#pragma unroll
    for (int o = 1; o < 64; o <<= 1) var += __shfl_xor(var, o);
    __syncthreads();
    if ((tid & 63) == 0) sbuf[tid >> 6] = var;
    __syncthreads();
    var = (sbuf[0] + sbuf[1] + sbuf[2] + sbuf[3]) * (1.f / 768.f);
    const float rs = rsqrtf(var + 1e-5f);
#pragma unroll
    for (int i = 0; i < 3; i++) {
        int idx = tid + i * 256;
        u[base + idx] = f2bf((v[i] - mean) * rs * g[idx] + b[idx]);
    }
}

// ---------------- big GEMM: C[M,N] = A[M,K]*B[N,K]^T, bf16 in, bf16 or fp32 out ----------------
template<bool F32OUT>
__global__ __launch_bounds__(256) void gemm_bt(
    const u16* __restrict__ A, int lda, const u16* __restrict__ B, int ldb,
    void* __restrict__ Cv, int ldc, int K)
{
    __shared__ uint4 As[512];
    __shared__ uint4 Bs[512];
    const int tid = threadIdx.x;
    const int wid = tid >> 6;
    const int lane = tid & 63;
    const int m0 = blockIdx.y * 128;
    const int n0 = blockIdx.x * 128;
    const int wm = (wid >> 1) * 64;
    const int wn = (wid & 1) * 64;
    f32x4 acc[4][4];
#pragma unroll
    for (int i = 0; i < 4; i++)
#pragma unroll
        for (int j = 0; j < 4; j++) acc[i][j] = (f32x4){0.f, 0.f, 0.f, 0.f};

    const int r0 = tid >> 2;
    const int cq = tid & 3;
    const uint4* pa0 = (const uint4*)(A + (size_t)(m0 + r0) * lda) + cq;
    const uint4* pa1 = (const uint4*)(A + (size_t)(m0 + 64 + r0) * lda) + cq;
    const uint4* pb0 = (const uint4*)(B + (size_t)(n0 + r0) * ldb) + cq;
    const uint4* pb1 = (const uint4*)(B + (size_t)(n0 + 64 + r0) * ldb) + cq;
    const int fr = lane & 15;
    const int kq = lane >> 4;

    for (int k0 = 0; k0 < K; k0 += 32) {
        const int kk = k0 >> 3;
        uint4 a0 = pa0[kk];
        uint4 a1 = pa1[kk];
        uint4 b0 = pb0[kk];
        uint4 b1 = pb1[kk];
        __syncthreads();
        As[r0 * 4 + cq] = a0;
        As[(64 + r0) * 4 + cq] = a1;
        Bs[r0 * 4 + cq] = b0;
        Bs[(64 + r0) * 4 + cq] = b1;
        __syncthreads();
        bf16x8 af[4], bfr[4];
#pragma unroll
        for (int i = 0; i < 4; i++) {
            af[i]  = __builtin_bit_cast(bf16x8, As[(wm + i * 16 + fr) * 4 + kq]);
            bfr[i] = __builtin_bit_cast(bf16x8, Bs[(wn + i * 16 + fr) * 4 + kq]);
        }
#pragma unroll
        for (int i = 0; i < 4; i++)
#pragma unroll
            for (int j = 0; j < 4; j++)
                acc[i][j] = __builtin_amdgcn_mfma_f32_16x16x32_bf16(af[i], bfr[j], acc[i][j], 0, 0, 0);
    }
    const int col = lane & 15;
    const int rb = (lane >> 4) * 4;
#pragma unroll
    for (int i = 0; i < 4; i++)
#pragma unroll
        for (int j = 0; j < 4; j++)
#pragma unroll
            for (int r = 0; r < 4; r++) {
                int m = m0 + wm + i * 16 + rb + r;
                int nn = n0 + wn + j * 16 + col;
                if (F32OUT)
                    ((float*)Cv)[(size_t)m * ldc + nn] = acc[i][j][r];
                else
                    ((u16*)Cv)[(size_t)m * ldc + nn] = f2bf(acc[i][j][r]);
            }
}

// ---------------- flexible small GEMM (K zero-padded), bf16 in/out, fp32 bias ----------------
template<int TM, int TN, int EPI>
__global__ __launch_bounds__(256) void gemm_bt_flex(
    const u16* __restrict__ A, int lda, const u16* __restrict__ B, int ldb,
    const float* __restrict__ bias, u16* __restrict__ C, int ldc, int K)
{
    constexpr int BM = 64 * TM;
    constexpr int BN = 16 * TN;
    __shared__ __align__(16) u32 As32[BM * 16];
    __shared__ __align__(16) u32 Bs32[BN * 16];
    const int tid = threadIdx.x;
    const int wid = tid >> 6;
    const int lane = tid & 63;
    const int m0 = blockIdx.y * BM;
    const int n0 = blockIdx.x * BN;
    f32x4 acc[TM][TN];
#pragma unroll
    for (int i = 0; i < TM; i++)
#pragma unroll
        for (int j = 0; j < TN; j++) acc[i][j] = (f32x4){0.f, 0.f, 0.f, 0.f};
    const int fr = lane & 15;
    const int kq = lane >> 4;
    const int ksteps = (K + 31) >> 5;

    for (int kt = 0; kt < ksteps; kt++) {
        const int k0 = kt * 32;
        __syncthreads();
        for (int e = tid; e < BM * 16; e += 256) {
            int r = e >> 4, c2 = (e & 15) * 2;
            int k = k0 + c2;
            u32 lo = (k < K)     ? (u32)A[(size_t)(m0 + r) * lda + k]     : 0u;
            u32 hi = (k + 1 < K) ? (u32)A[(size_t)(m0 + r) * lda + k + 1] : 0u;
            As32[e] = lo | (hi << 16);
        }
        for (int e = tid; e < BN * 16; e += 256) {
            int r = e >> 4, c2 = (e & 15) * 2;
            int k = k0 + c2;
            u32 lo = (k < K)     ? (u32)B[(size_t)(n0 + r) * ldb + k]     : 0u;
            u32 hi = (k + 1 < K) ? (u32)B[(size_t)(n0 + r) * ldb + k + 1] : 0u;
            Bs32[e] = lo | (hi << 16);
        }
        __syncthreads();
        bf16x8 af[TM], bfr[TN];
#pragma unroll
        for (int i = 0; i < TM; i++) {
            uint4 t4;
            __builtin_memcpy(&t4, &As32[(wid * 16 * TM + i * 16 + fr) * 16 + kq * 4], 16);
            af[i] = __builtin_bit_cast(bf16x8, t4);
        }
#pragma unroll
        for (int j = 0; j < TN; j++) {
            uint4 t4;
            __builtin_memcpy(&t4, &Bs32[(j * 16 + fr) * 16 + kq * 4], 16);
            bfr[j] = __builtin_bit_cast(bf16x8, t4);
        }
#pragma unroll
        for (int i = 0; i < TM; i++)
#pragma unroll
            for (int j = 0; j < TN; j++)
                acc[i][j] = __builtin_amdgcn_mfma_f32_16x16x32_bf16(af[i], bfr[j], acc[i][j], 0, 0, 0);
    }
    const int col = lane & 15;
    const int rb = (lane >> 4) * 4;
#pragma unroll
    for (int i = 0; i < TM; i++)
#pragma unroll
        for (int j = 0; j < TN; j++)
#pragma unroll
            for (int r = 0; r < 4; r++) {
                int m = m0 + wid * 16 * TM + i * 16 + rb + r;
                int nn = n0 + j * 16 + col;
                float v = acc[i][j][r];
                if (EPI == 1) {
                    v += bias[nn];
                    v = (v > 20.f) ? v : log1pf(__expf(v));
                }
                C[(size_t)m * ldc + nn] = f2bf(v);
            }
}

// ---------------- causal depthwise conv(4) + SiLU ----------------
__global__ __launch_bounds__(256) void conv_silu_kernel(
    const u16* __restrict__ xz, const float* __restrict__ cw, const float* __restrict__ cb,
    u16* __restrict__ xc)
{
    size_t i = (size_t)blockIdx.x * 256 + threadIdx.x;
    if (i >= (size_t)M_TOK * DINNER) return;
    int d = (int)(i % DINNER);
    size_t m = i / DINNER;
    int l = (int)(m & (SEQLEN - 1));
    float acc = cb[d];
#pragma unroll
    for (int k = 0; k < 4; k++) {
        int ls = l - 3 + k;
        if (ls >= 0)
            acc += bf2f(xz[(m - 3 + k) * (2 * DINNER) + d]) * cw[d * 4 + k];
    }
    xc[i] = f2bf(acc / (1.f + __expf(-acc)));
}

// ========== chunked selective scan: lane-per-d, n in registers ==========
// Phase A: local scan per chunk (h=0), emit S=sum(dt) and local h_final (bf16)
__global__ __launch_bounds__(256) void scan_partA(
    const u16* __restrict__ dtp, const u16* __restrict__ xc, const u16* __restrict__ proj,
    const float* __restrict__ Alog,
    float* __restrict__ Sbuf, uint4* __restrict__ Hfin)
{
    const int d = blockIdx.x * 256 + threadIdx.x;
    const int c = blockIdx.y;
    const int b = blockIdx.z;
    float A[16], h[16];
#pragma unroll
    for (int n = 0; n < 16; n++) {
        A[n] = -__expf(Alog[(size_t)d * 16 + n]);
        h[n] = 0.f;
    }
    float S = 0.f;
    const size_t tbase = (size_t)b * SEQLEN + (size_t)c * CLEN;
    for (int t = 0; t < CLEN; t++) {
        const size_t tt = tbase + t;
        float dt = bf2f(dtp[tt * DINNER + d]);
        float x  = bf2f(xc[tt * DINNER + d]);
        const uint4* prow = (const uint4*)(proj + tt * 80);
        float Bv[16];
        unpack8(prow[6], Bv);
        unpack8(prow[7], Bv + 8);
        S += dt;
        float bx = dt * x;
#pragma unroll
        for (int n = 0; n < 16; n++)
            h[n] = fmaf(__expf(dt * A[n]), h[n], bx * Bv[n]);
    }
    const size_t idx = ((size_t)(b * NCHUNK + c) * DINNER + d);
    Sbuf[idx] = S;
    Hfin[idx * 2]     = pack8(h);
    Hfin[idx * 2 + 1] = pack8(h + 8);
}

// Phase B: sequential combine over chunks -> h_in per chunk (bf16)
__global__ __launch_bounds__(256) void scan_partB(
    const float* __restrict__ Sbuf, const uint4* __restrict__ Hfin,
    const float* __restrict__ Alog, uint4* __restrict__ Hin)
{
    const int id = blockIdx.x * 256 + threadIdx.x;   // over 4*1536
    const int b = id / DINNER;
    const int d = id - b * DINNER;
    float A[16], h[16];
#pragma unroll
    for (int n = 0; n < 16; n++) {
        A[n] = -__expf(Alog[(size_t)d * 16 + n]);
        h[n] = 0.f;
    }
    for (int c = 0; c < NCHUNK; c++) {
        const size_t idx = ((size_t)(b * NCHUNK + c) * DINNER + d);
        Hin[idx * 2]     = pack8(h);
        Hin[idx * 2 + 1] = pack8(h + 8);
        float S = Sbuf[idx];
        float hf[16];
        unpack8(Hfin[idx * 2], hf);
        unpack8(Hfin[idx * 2 + 1], hf + 8);
#pragma unroll
        for (int n = 0; n < 16; n++)
            h[n] = fmaf(__expf(A[n] * S), h[n], hf[n]);
    }
}

// Phase C: full scan per chunk from h_in; fused +x*D and *silu(z); y -> xs half of xz
__global__ __launch_bounds__(256) void scan_partC(
    const u16* __restrict__ dtp, const u16* __restrict__ xc, const u16* __restrict__ proj,
    u16* xz, const float* __restrict__ Alog, const float* __restrict__ Dp,
    const uint4* __restrict__ Hin)
{
    const int d = blockIdx.x * 256 + threadIdx.x;
    const int c = blockIdx.y;
    const int b = blockIdx.z;
    float A[16], h[16];
#pragma unroll
    for (int n = 0; n < 16; n++)
        A[n] = -__expf(Alog[(size_t)d * 16 + n]);
    {
        const size_t idx = ((size_t)(b * NCHUNK + c) * DINNER + d);
        unpack8(Hin[idx * 2], h);
        unpack8(Hin[idx * 2 + 1], h + 8);
    }
    const float D_d = Dp[d];
    const size_t tbase = (size_t)b * SEQLEN + (size_t)c * CLEN;
    for (int t = 0; t < CLEN; t++) {
        const size_t tt = tbase + t;
        float dt = bf2f(dtp[tt * DINNER + d]);
        float x  = bf2f(xc[tt * DINNER + d]);
        float z  = bf2f(xz[tt * (2 * DINNER) + DINNER + d]);
        const uint4* prow = (const uint4*)(proj + tt * 80);
        float Bv[16], Cv[16];
        unpack8(prow[6], Bv);
        unpack8(prow[7], Bv + 8);
        unpack8(prow[8], Cv);
        unpack8(prow[9], Cv + 8);
        float bx = dt * x;
        float y = 0.f;
#pragma unroll
        for (int n = 0; n < 16; n++) {
            h[n] = fmaf(__expf(dt * A[n]), h[n], bx * Bv[n]);
            y = fmaf(h[n], Cv[n], y);
        }
        float yv = (y + x * D_d) * (z / (1.f + __expf(-z)));
        xz[tt * (2 * DINNER) + d] = f2bf(yv);   // dead xs slot
    }
}

extern "C" void kernel_launch(void* const* d_in, const int* in_sizes, int n_in,
                              void* d_out, int out_size, void* d_ws, size_t ws_size,
                              hipStream_t stream) {
    (void)in_sizes; (void)n_in; (void)out_size; (void)ws_size;
    const float* x    = (const float*)d_in[0];
    const float* res  = (const float*)d_in[1];
    const float* lng  = (const float*)d_in[2];
    const float* lnb  = (const float*)d_in[3];
    const float* Win  = (const float*)d_in[4];
    const float* cw   = (const float*)d_in[5];
    const float* cb   = (const float*)d_in[6];
    const float* Wxp  = (const float*)d_in[7];
    const float* Wdt  = (const float*)d_in[8];
    const float* bdt  = (const float*)d_in[9];
    const float* Alog = (const float*)d_in[10];
    const float* Dp   = (const float*)d_in[11];
    const float* Wout = (const float*)d_in[12];

    float* out = (float*)d_out;
    float* res_out = out + (size_t)M_TOK * DMODEL;

    char* ws = (char*)d_ws;
    u16* xz_buf = (u16*)(ws);                  // 50,331,648
    u16* xc_buf = (u16*)(ws + 50331648);       // 25,165,824
    u16* dt_buf = (u16*)(ws + 75497472);       // 25,165,824
    u16* u_buf  = dt_buf;                      // disjoint lifetime with dt
    u16* pj_buf = (u16*)(ws + 100663296);      //  1,310,720
    u16* Winb   = (u16*)(ws + 101974016);      //  4,718,592
    u16* Woutb  = (u16*)(ws + 106692608);      //  2,359,296
    u16* Wxpb   = (u16*)(ws + 109051904);      //    245,760
    u16* Wdtb   = (u16*)(ws + 109297664);      //    147,456
    float* Sbuf = (float*)(ws + 109445120);    //    786,432
    uint4* Hfin = (uint4*)(ws + 110231552);    //  6,291,456 (bf16 h)
    uint4* Hin  = (uint4*)(ws + 116523008);    //  6,291,456 (end ~122.8 MB)

    // 0. convert weights fp32 -> bf16
    cvt_kernel<<<(3072 * 768 / 4 + 255) / 256, 256, 0, stream>>>(Win, Winb, 3072 * 768 / 4);
    cvt_kernel<<<(768 * 1536 / 4 + 255) / 256, 256, 0, stream>>>(Wout, Woutb, 768 * 1536 / 4);
    cvt_kernel<<<(80 * 1536 / 4 + 255) / 256, 256, 0, stream>>>(Wxp, Wxpb, 80 * 1536 / 4);
    cvt_kernel<<<(1536 * 48 / 4 + 255) / 256, 256, 0, stream>>>(Wdt, Wdtb, 1536 * 48 / 4);
    // 1. res+x (fp32 out), layernorm (bf16 u)
    ln_kernel<<<M_TOK, 256, 0, stream>>>(x, res, lng, lnb, res_out, u_buf);
    // 2. in_proj
    gemm_bt<false><<<dim3(3072 / 128, M_TOK / 128), 256, 0, stream>>>(
        u_buf, DMODEL, Winb, DMODEL, xz_buf, 2 * DINNER, DMODEL);
    // 3. conv + silu
    conv_silu_kernel<<<(M_TOK * DINNER) / 256, 256, 0, stream>>>(xz_buf, cw, cb, xc_buf);
    // 4. x_proj
    gemm_bt_flex<1, 5, 0><<<dim3(1, M_TOK / 64), 256, 0, stream>>>(
        xc_buf, DINNER, Wxpb, DINNER, (const float*)nullptr, pj_buf, 80, DINNER);
    // 5. dt = softplus(...)
    gemm_bt_flex<1, 8, 1><<<dim3(DINNER / 128, M_TOK / 64), 256, 0, stream>>>(
        pj_buf, 80, Wdtb, DTRANK, bdt, dt_buf, DINNER, DTRANK);
    // 6. chunked selective scan
    scan_partA<<<dim3(DINNER / 256, NCHUNK, 4), 256, 0, stream>>>(
        dt_buf, xc_buf, pj_buf, Alog, Sbuf, Hfin);
    scan_partB<<<(4 * DINNER) / 256, 256, 0, stream>>>(Sbuf, Hfin, Alog, Hin);
    scan_partC<<<dim3(DINNER / 256, NCHUNK, 4), 256, 0, stream>>>(
        dt_buf, xc_buf, pj_buf, xz_buf, Alog, Dp, Hin);
    // 7. out_proj (fp32 out), y strided in xz
    gemm_bt<true><<<dim3(DMODEL / 128, M_TOK / 128), 256, 0, stream>>>(
        xz_buf, 2 * DINNER, Woutb, DINNER, out, DMODEL, DINNER);
}

// Round 7
// 487.582 us; speedup vs baseline: 2.2607x; 1.2342x over previous
//
#include <hip/hip_runtime.h>

typedef unsigned short u16;
typedef unsigned int u32;
typedef __bf16 bf16x8 __attribute__((ext_vector_type(8)));
typedef float f32x4 __attribute__((ext_vector_type(4)));

#define M_TOK 8192
#define DMODEL 768
#define DINNER 1536
#define NSTATE 16
#define DTRANK 48
#define SEQLEN 2048
#define NCHUNK 32
#define CLEN 64          // SEQLEN / NCHUNK
#define XP_KS 8          // x_proj K-splits

__device__ __forceinline__ float bf2f(u16 v) {
    return __builtin_bit_cast(float, (u32)v << 16);
}
__device__ __forceinline__ u16 f2bf(float f) {
    u32 u = __builtin_bit_cast(u32, f);
    return (u16)((u + 0x7FFFu + ((u >> 16) & 1u)) >> 16);
}
__device__ __forceinline__ void unpack8(uint4 q, float* f) {
    u32 w[4] = {q.x, q.y, q.z, q.w};
#pragma unroll
    for (int i = 0; i < 4; i++) {
        f[2 * i]     = bf2f((u16)(w[i] & 0xffffu));
        f[2 * i + 1] = bf2f((u16)(w[i] >> 16));
    }
}
__device__ __forceinline__ uint4 pack8(const float* f) {
    uint4 q;
    q.x = (u32)f2bf(f[0]) | ((u32)f2bf(f[1]) << 16);
    q.y = (u32)f2bf(f[2]) | ((u32)f2bf(f[3]) << 16);
    q.z = (u32)f2bf(f[4]) | ((u32)f2bf(f[5]) << 16);
    q.w = (u32)f2bf(f[6]) | ((u32)f2bf(f[7]) << 16);
    return q;
}

// ---------------- fp32 -> bf16 converter (n % 4 == 0) ----------------
__global__ __launch_bounds__(256) void cvt_kernel(
    const float* __restrict__ src, u16* __restrict__ dst, int n4)
{
    int i = blockIdx.x * 256 + threadIdx.x;
    if (i >= n4) return;
    float4 v = ((const float4*)src)[i];
    ushort4 o;
    o.x = f2bf(v.x); o.y = f2bf(v.y); o.z = f2bf(v.z); o.w = f2bf(v.w);
    ((ushort4*)dst)[i] = o;
}

// ---------------- fused residual add + layernorm (fp32 in, fp32 res_out, bf16 u) ----------------
__global__ __launch_bounds__(256) void ln_kernel(
    const float* __restrict__ x, const float* __restrict__ res,
    const float* __restrict__ g, const float* __restrict__ b,
    float* __restrict__ res_out, u16* __restrict__ u)
{
    __shared__ float sbuf[4];
    const int row = blockIdx.x;
    const int tid = threadIdx.x;
    const size_t base = (size_t)row * DMODEL;
    float v[3];
    float s = 0.f;
#pragma unroll
    for (int i = 0; i < 3; i++) {
        int idx = tid + i * 256;
        v[i] = x[base + idx] + res[base + idx];
        res_out[base + idx] = v[i];
        s += v[i];
    }
#pragma unroll
    for (int o = 1; o < 64; o <<= 1) s += __shfl_xor(s, o);
    if ((tid & 63) == 0) sbuf[tid >> 6] = s;
    __syncthreads();
    s = sbuf[0] + sbuf[1] + sbuf[2] + sbuf[3];
    const float mean = s * (1.f / 768.f);
    float var = 0.f;
#pragma unroll
    for (int i = 0; i < 3; i++) { float d = v[i] - mean; var += d * d; }
#pragma unroll
    for (int o = 1; o < 64; o <<= 1) var += __shfl_xor(var, o);
    __syncthreads();
    if ((tid & 63) == 0) sbuf[tid >> 6] = var;
    __syncthreads();
    var = (sbuf[0] + sbuf[1] + sbuf[2] + sbuf[3]) * (1.f / 768.f);
    const float rs = rsqrtf(var + 1e-5f);
#pragma unroll
    for (int i = 0; i < 3; i++) {
        int idx = tid + i * 256;
        u[base + idx] = f2bf((v[i] - mean) * rs * g[idx] + b[idx]);
    }
}

// ---------------- big GEMM: C[M,N] = A[M,K]*B[N,K]^T, bf16 in, bf16 or fp32 out ----------------
template<bool F32OUT>
__global__ __launch_bounds__(256) void gemm_bt(
    const u16* __restrict__ A, int lda, const u16* __restrict__ B, int ldb,
    void* __restrict__ Cv, int ldc, int K)
{
    __shared__ uint4 As[512];
    __shared__ uint4 Bs[512];
    const int tid = threadIdx.x;
    const int wid = tid >> 6;
    const int lane = tid & 63;
    const int m0 = blockIdx.y * 128;
    const int n0 = blockIdx.x * 128;
    const int wm = (wid >> 1) * 64;
    const int wn = (wid & 1) * 64;
    f32x4 acc[4][4];
#pragma unroll
    for (int i = 0; i < 4; i++)
#pragma unroll
        for (int j = 0; j < 4; j++) acc[i][j] = (f32x4){0.f, 0.f, 0.f, 0.f};

    const int r0 = tid >> 2;
    const int cq = tid & 3;
    const uint4* pa0 = (const uint4*)(A + (size_t)(m0 + r0) * lda) + cq;
    const uint4* pa1 = (const uint4*)(A + (size_t)(m0 + 64 + r0) * lda) + cq;
    const uint4* pb0 = (const uint4*)(B + (size_t)(n0 + r0) * ldb) + cq;
    const uint4* pb1 = (const uint4*)(B + (size_t)(n0 + 64 + r0) * ldb) + cq;
    const int fr = lane & 15;
    const int kq = lane >> 4;

    for (int k0 = 0; k0 < K; k0 += 32) {
        const int kk = k0 >> 3;
        uint4 a0 = pa0[kk];
        uint4 a1 = pa1[kk];
        uint4 b0 = pb0[kk];
        uint4 b1 = pb1[kk];
        __syncthreads();
        As[r0 * 4 + cq] = a0;
        As[(64 + r0) * 4 + cq] = a1;
        Bs[r0 * 4 + cq] = b0;
        Bs[(64 + r0) * 4 + cq] = b1;
        __syncthreads();
        bf16x8 af[4], bfr[4];
#pragma unroll
        for (int i = 0; i < 4; i++) {
            af[i]  = __builtin_bit_cast(bf16x8, As[(wm + i * 16 + fr) * 4 + kq]);
            bfr[i] = __builtin_bit_cast(bf16x8, Bs[(wn + i * 16 + fr) * 4 + kq]);
        }
#pragma unroll
        for (int i = 0; i < 4; i++)
#pragma unroll
            for (int j = 0; j < 4; j++)
                acc[i][j] = __builtin_amdgcn_mfma_f32_16x16x32_bf16(af[i], bfr[j], acc[i][j], 0, 0, 0);
    }
    const int col = lane & 15;
    const int rb = (lane >> 4) * 4;
#pragma unroll
    for (int i = 0; i < 4; i++)
#pragma unroll
        for (int j = 0; j < 4; j++)
#pragma unroll
            for (int r = 0; r < 4; r++) {
                int m = m0 + wm + i * 16 + rb + r;
                int nn = n0 + wn + j * 16 + col;
                if (F32OUT)
                    ((float*)Cv)[(size_t)m * ldc + nn] = acc[i][j][r];
                else
                    ((u16*)Cv)[(size_t)m * ldc + nn] = f2bf(acc[i][j][r]);
            }
}

// ---------------- split-K x_proj: P[ks][M][80] partial = A[M,Kslice]*B[80,Kslice]^T ----------------
__global__ __launch_bounds__(256) void gemm_xproj(
    const u16* __restrict__ A, const u16* __restrict__ B, float* __restrict__ P)
{
    __shared__ uint4 As[256];       // 64 rows x 4 uint4
    __shared__ uint4 Bs[320];       // 80 rows x 4 uint4
    const int tid = threadIdx.x;
    const int wid = tid >> 6;
    const int lane = tid & 63;
    const int m0 = blockIdx.y * 64;
    const int kbase = blockIdx.x * (DINNER / XP_KS);    // 192-wide K slice
    f32x4 acc[5];
#pragma unroll
    for (int j = 0; j < 5; j++) acc[j] = (f32x4){0.f, 0.f, 0.f, 0.f};

    const int ra = tid >> 2;   // A staging row
    const int qa = tid & 3;    // uint4 col
    const int fr = lane & 15;
    const int kq = lane >> 4;

    for (int ks = 0; ks < DINNER / XP_KS; ks += 32) {
        const int k0 = kbase + ks;
        uint4 av = *((const uint4*)(A + (size_t)(m0 + ra) * DINNER + k0) + qa);
        uint4 bv0, bv1;
        {
            int e = tid;               // 0..255
            int rb_ = e >> 2, qb = e & 3;
            bv0 = *((const uint4*)(B + (size_t)rb_ * DINNER + k0) + qb);
            int e2 = tid + 256;        // 256..319 (only first 64 threads)
            int rb2 = e2 >> 2, qb2 = e2 & 3;
            bv1 = (e2 < 320) ? *((const uint4*)(B + (size_t)rb2 * DINNER + k0) + qb2)
                             : (uint4){0, 0, 0, 0};
        }
        __syncthreads();
        As[ra * 4 + qa] = av;
        Bs[tid] = bv0;
        if (tid < 64) Bs[tid + 256] = bv1;
        __syncthreads();
        bf16x8 af = __builtin_bit_cast(bf16x8, As[(wid * 16 + fr) * 4 + kq]);
#pragma unroll
        for (int j = 0; j < 5; j++) {
            bf16x8 bf = __builtin_bit_cast(bf16x8, Bs[(j * 16 + fr) * 4 + kq]);
            acc[j] = __builtin_amdgcn_mfma_f32_16x16x32_bf16(af, bf, acc[j], 0, 0, 0);
        }
    }
    const int col = lane & 15;
    const int rb = (lane >> 4) * 4;
    float* Pb = P + (size_t)blockIdx.x * M_TOK * 80;
#pragma unroll
    for (int j = 0; j < 5; j++)
#pragma unroll
        for (int r = 0; r < 4; r++) {
            int m = m0 + wid * 16 + rb + r;
            Pb[(size_t)m * 80 + j * 16 + col] = acc[j][r];
        }
}

// reduce XP_KS fp32 partials -> bf16 pj
__global__ __launch_bounds__(256) void xproj_reduce(
    const float* __restrict__ P, u16* __restrict__ pj)
{
    int i = blockIdx.x * 256 + threadIdx.x;   // over 8192*80
    float s = 0.f;
#pragma unroll
    for (int ks = 0; ks < XP_KS; ks++)
        s += P[(size_t)ks * M_TOK * 80 + i];
    pj[i] = f2bf(s);
}

// ---------------- flexible small GEMM (K zero-padded), bf16 in/out, fp32 bias ----------------
template<int TM, int TN, int EPI>
__global__ __launch_bounds__(256) void gemm_bt_flex(
    const u16* __restrict__ A, int lda, const u16* __restrict__ B, int ldb,
    const float* __restrict__ bias, u16* __restrict__ C, int ldc, int K)
{
    constexpr int BM = 64 * TM;
    constexpr int BN = 16 * TN;
    __shared__ __align__(16) u32 As32[BM * 16];
    __shared__ __align__(16) u32 Bs32[BN * 16];
    const int tid = threadIdx.x;
    const int wid = tid >> 6;
    const int lane = tid & 63;
    const int m0 = blockIdx.y * BM;
    const int n0 = blockIdx.x * BN;
    f32x4 acc[TM][TN];
#pragma unroll
    for (int i = 0; i < TM; i++)
#pragma unroll
        for (int j = 0; j < TN; j++) acc[i][j] = (f32x4){0.f, 0.f, 0.f, 0.f};
    const int fr = lane & 15;
    const int kq = lane >> 4;
    const int ksteps = (K + 31) >> 5;

    for (int kt = 0; kt < ksteps; kt++) {
        const int k0 = kt * 32;
        __syncthreads();
        for (int e = tid; e < BM * 16; e += 256) {
            int r = e >> 4, c2 = (e & 15) * 2;
            int k = k0 + c2;
            u32 lo = (k < K)     ? (u32)A[(size_t)(m0 + r) * lda + k]     : 0u;
            u32 hi = (k + 1 < K) ? (u32)A[(size_t)(m0 + r) * lda + k + 1] : 0u;
            As32[e] = lo | (hi << 16);
        }
        for (int e = tid; e < BN * 16; e += 256) {
            int r = e >> 4, c2 = (e & 15) * 2;
            int k = k0 + c2;
            u32 lo = (k < K)     ? (u32)B[(size_t)(n0 + r) * ldb + k]     : 0u;
            u32 hi = (k + 1 < K) ? (u32)B[(size_t)(n0 + r) * ldb + k + 1] : 0u;
            Bs32[e] = lo | (hi << 16);
        }
        __syncthreads();
        bf16x8 af[TM], bfr[TN];
#pragma unroll
        for (int i = 0; i < TM; i++) {
            uint4 t4;
            __builtin_memcpy(&t4, &As32[(wid * 16 * TM + i * 16 + fr) * 16 + kq * 4], 16);
            af[i] = __builtin_bit_cast(bf16x8, t4);
        }
#pragma unroll
        for (int j = 0; j < TN; j++) {
            uint4 t4;
            __builtin_memcpy(&t4, &Bs32[(j * 16 + fr) * 16 + kq * 4], 16);
            bfr[j] = __builtin_bit_cast(bf16x8, t4);
        }
#pragma unroll
        for (int i = 0; i < TM; i++)
#pragma unroll
            for (int j = 0; j < TN; j++)
                acc[i][j] = __builtin_amdgcn_mfma_f32_16x16x32_bf16(af[i], bfr[j], acc[i][j], 0, 0, 0);
    }
    const int col = lane & 15;
    const int rb = (lane >> 4) * 4;
#pragma unroll
    for (int i = 0; i < TM; i++)
#pragma unroll
        for (int j = 0; j < TN; j++)
#pragma unroll
            for (int r = 0; r < 4; r++) {
                int m = m0 + wid * 16 * TM + i * 16 + rb + r;
                int nn = n0 + j * 16 + col;
                float v = acc[i][j][r];
                if (EPI == 1) {
                    v += bias[nn];
                    v = (v > 20.f) ? v : log1pf(__expf(v));
                }
                C[(size_t)m * ldc + nn] = f2bf(v);
            }
}

// ---------------- causal depthwise conv(4) + SiLU ----------------
__global__ __launch_bounds__(256) void conv_silu_kernel(
    const u16* __restrict__ xz, const float* __restrict__ cw, const float* __restrict__ cb,
    u16* __restrict__ xc)
{
    size_t i = (size_t)blockIdx.x * 256 + threadIdx.x;
    if (i >= (size_t)M_TOK * DINNER) return;
    int d = (int)(i % DINNER);
    size_t m = i / DINNER;
    int l = (int)(m & (SEQLEN - 1));
    float acc = cb[d];
#pragma unroll
    for (int k = 0; k < 4; k++) {
        int ls = l - 3 + k;
        if (ls >= 0)
            acc += bf2f(xz[(m - 3 + k) * (2 * DINNER) + d]) * cw[d * 4 + k];
    }
    xc[i] = f2bf(acc / (1.f + __expf(-acc)));
}

// ========== chunked selective scan: lane-per-d, n in registers ==========
__global__ __launch_bounds__(256) void scan_partA(
    const u16* __restrict__ dtp, const u16* __restrict__ xc, const u16* __restrict__ proj,
    const float* __restrict__ Alog,
    float* __restrict__ Sbuf, uint4* __restrict__ Hfin)
{
    const int d = blockIdx.x * 256 + threadIdx.x;
    const int c = blockIdx.y;
    const int b = blockIdx.z;
    float A[16], h[16];
#pragma unroll
    for (int n = 0; n < 16; n++) {
        A[n] = -__expf(Alog[(size_t)d * 16 + n]);
        h[n] = 0.f;
    }
    float S = 0.f;
    const size_t tbase = (size_t)b * SEQLEN + (size_t)c * CLEN;
    for (int t = 0; t < CLEN; t++) {
        const size_t tt = tbase + t;
        float dt = bf2f(dtp[tt * DINNER + d]);
        float x  = bf2f(xc[tt * DINNER + d]);
        const uint4* prow = (const uint4*)(proj + tt * 80);
        float Bv[16];
        unpack8(prow[6], Bv);
        unpack8(prow[7], Bv + 8);
        S += dt;
        float bx = dt * x;
#pragma unroll
        for (int n = 0; n < 16; n++)
            h[n] = fmaf(__expf(dt * A[n]), h[n], bx * Bv[n]);
    }
    const size_t idx = ((size_t)(b * NCHUNK + c) * DINNER + d);
    Sbuf[idx] = S;
    Hfin[idx * 2]     = pack8(h);
    Hfin[idx * 2 + 1] = pack8(h + 8);
}

__global__ __launch_bounds__(256) void scan_partB(
    const float* __restrict__ Sbuf, const uint4* __restrict__ Hfin,
    const float* __restrict__ Alog, uint4* __restrict__ Hin)
{
    const int id = blockIdx.x * 256 + threadIdx.x;
    const int b = id / DINNER;
    const int d = id - b * DINNER;
    float A[16], h[16];
#pragma unroll
    for (int n = 0; n < 16; n++) {
        A[n] = -__expf(Alog[(size_t)d * 16 + n]);
        h[n] = 0.f;
    }
    for (int c = 0; c < NCHUNK; c++) {
        const size_t idx = ((size_t)(b * NCHUNK + c) * DINNER + d);
        Hin[idx * 2]     = pack8(h);
        Hin[idx * 2 + 1] = pack8(h + 8);
        float S = Sbuf[idx];
        float hf[16];
        unpack8(Hfin[idx * 2], hf);
        unpack8(Hfin[idx * 2 + 1], hf + 8);
#pragma unroll
        for (int n = 0; n < 16; n++)
            h[n] = fmaf(__expf(A[n] * S), h[n], hf[n]);
    }
}

__global__ __launch_bounds__(256) void scan_partC(
    const u16* __restrict__ dtp, const u16* __restrict__ xc, const u16* __restrict__ proj,
    u16* xz, const float* __restrict__ Alog, const float* __restrict__ Dp,
    const uint4* __restrict__ Hin)
{
    const int d = blockIdx.x * 256 + threadIdx.x;
    const int c = blockIdx.y;
    const int b = blockIdx.z;
    float A[16], h[16];
#pragma unroll
    for (int n = 0; n < 16; n++)
        A[n] = -__expf(Alog[(size_t)d * 16 + n]);
    {
        const size_t idx = ((size_t)(b * NCHUNK + c) * DINNER + d);
        unpack8(Hin[idx * 2], h);
        unpack8(Hin[idx * 2 + 1], h + 8);
    }
    const float D_d = Dp[d];
    const size_t tbase = (size_t)b * SEQLEN + (size_t)c * CLEN;
    for (int t = 0; t < CLEN; t++) {
        const size_t tt = tbase + t;
        float dt = bf2f(dtp[tt * DINNER + d]);
        float x  = bf2f(xc[tt * DINNER + d]);
        float z  = bf2f(xz[tt * (2 * DINNER) + DINNER + d]);
        const uint4* prow = (const uint4*)(proj + tt * 80);
        float Bv[16], Cv[16];
        unpack8(prow[6], Bv);
        unpack8(prow[7], Bv + 8);
        unpack8(prow[8], Cv);
        unpack8(prow[9], Cv + 8);
        float bx = dt * x;
        float y = 0.f;
#pragma unroll
        for (int n = 0; n < 16; n++) {
            h[n] = fmaf(__expf(dt * A[n]), h[n], bx * Bv[n]);
            y = fmaf(h[n], Cv[n], y);
        }
        float yv = (y + x * D_d) * (z / (1.f + __expf(-z)));
        xz[tt * (2 * DINNER) + d] = f2bf(yv);
    }
}

extern "C" void kernel_launch(void* const* d_in, const int* in_sizes, int n_in,
                              void* d_out, int out_size, void* d_ws, size_t ws_size,
                              hipStream_t stream) {
    (void)in_sizes; (void)n_in; (void)out_size; (void)ws_size;
    const float* x    = (const float*)d_in[0];
    const float* res  = (const float*)d_in[1];
    const float* lng  = (const float*)d_in[2];
    const float* lnb  = (const float*)d_in[3];
    const float* Win  = (const float*)d_in[4];
    const float* cw   = (const float*)d_in[5];
    const float* cb   = (const float*)d_in[6];
    const float* Wxp  = (const float*)d_in[7];
    const float* Wdt  = (const float*)d_in[8];
    const float* bdt  = (const float*)d_in[9];
    const float* Alog = (const float*)d_in[10];
    const float* Dp   = (const float*)d_in[11];
    const float* Wout = (const float*)d_in[12];

    float* out = (float*)d_out;
    float* res_out = out + (size_t)M_TOK * DMODEL;

    char* ws = (char*)d_ws;
    u16* xz_buf = (u16*)(ws);                  // 50,331,648
    u16* xc_buf = (u16*)(ws + 50331648);       // 25,165,824
    u16* dt_buf = (u16*)(ws + 75497472);       // 25,165,824
    u16* u_buf  = dt_buf;                      // disjoint lifetime with dt
    float* Pbuf = (float*)(ws + 75497472);     // x_proj partials 8*8192*80*4 = 20,971,520 (dt region, disjoint lifetime)
    u16* pj_buf = (u16*)(ws + 100663296);      //  1,310,720
    u16* Winb   = (u16*)(ws + 101974016);      //  4,718,592
    u16* Woutb  = (u16*)(ws + 106692608);      //  2,359,296
    u16* Wxpb   = (u16*)(ws + 109051904);      //    245,760
    u16* Wdtb   = (u16*)(ws + 109297664);      //    147,456
    float* Sbuf = (float*)(ws + 109445120);    //    786,432
    uint4* Hfin = (uint4*)(ws + 110231552);    //  6,291,456
    uint4* Hin  = (uint4*)(ws + 116523008);    //  6,291,456 (end ~122.8 MB)

    // 0. convert weights fp32 -> bf16
    cvt_kernel<<<(3072 * 768 / 4 + 255) / 256, 256, 0, stream>>>(Win, Winb, 3072 * 768 / 4);
    cvt_kernel<<<(768 * 1536 / 4 + 255) / 256, 256, 0, stream>>>(Wout, Woutb, 768 * 1536 / 4);
    cvt_kernel<<<(80 * 1536 / 4 + 255) / 256, 256, 0, stream>>>(Wxp, Wxpb, 80 * 1536 / 4);
    cvt_kernel<<<(1536 * 48 / 4 + 255) / 256, 256, 0, stream>>>(Wdt, Wdtb, 1536 * 48 / 4);
    // 1. res+x (fp32 out), layernorm (bf16 u)
    ln_kernel<<<M_TOK, 256, 0, stream>>>(x, res, lng, lnb, res_out, u_buf);
    // 2. in_proj
    gemm_bt<false><<<dim3(3072 / 128, M_TOK / 128), 256, 0, stream>>>(
        u_buf, DMODEL, Winb, DMODEL, xz_buf, 2 * DINNER, DMODEL);
    // 3. conv + silu
    conv_silu_kernel<<<(M_TOK * DINNER) / 256, 256, 0, stream>>>(xz_buf, cw, cb, xc_buf);
    // 4. x_proj: split-K partials + reduce
    gemm_xproj<<<dim3(XP_KS, M_TOK / 64), 256, 0, stream>>>(xc_buf, Wxpb, Pbuf);
    xproj_reduce<<<(M_TOK * 80) / 256, 256, 0, stream>>>(Pbuf, pj_buf);
    // 5. dt = softplus(proj[:, :48] @ W_dt^T + b_dt)
    gemm_bt_flex<1, 8, 1><<<dim3(DINNER / 128, M_TOK / 64), 256, 0, stream>>>(
        pj_buf, 80, Wdtb, DTRANK, bdt, dt_buf, DINNER, DTRANK);
    // 6. chunked selective scan
    scan_partA<<<dim3(DINNER / 256, NCHUNK, 4), 256, 0, stream>>>(
        dt_buf, xc_buf, pj_buf, Alog, Sbuf, Hfin);
    scan_partB<<<(4 * DINNER) / 256, 256, 0, stream>>>(Sbuf, Hfin, Alog, Hin);
    scan_partC<<<dim3(DINNER / 256, NCHUNK, 4), 256, 0, stream>>>(
        dt_buf, xc_buf, pj_buf, xz_buf, Alog, Dp, Hin);
    // 7. out_proj (fp32 out), y strided in xz
    gemm_bt<true><<<dim3(DMODEL / 128, M_TOK / 128), 256, 0, stream>>>(
        xz_buf, 2 * DINNER, Woutb, DINNER, out, DMODEL, DINNER);
}

// Round 9
// 482.956 us; speedup vs baseline: 2.2823x; 1.0096x over previous
//
#include <hip/hip_runtime.h>

typedef unsigned short u16;
typedef unsigned int u32;
typedef __bf16 bf16x8 __attribute__((ext_vector_type(8)));
typedef float f32x4 __attribute__((ext_vector_type(4)));

#define M_TOK 8192
#define DMODEL 768
#define DINNER 1536
#define NSTATE 16
#define DTRANK 48
#define SEQLEN 2048
#define NCHUNK 32
#define CLEN 64          // SEQLEN / NCHUNK
#define XP_KS 8          // x_proj K-splits

__device__ __forceinline__ float bf2f(u16 v) {
    return __builtin_bit_cast(float, (u32)v << 16);
}
__device__ __forceinline__ u16 f2bf(float f) {
    u32 u = __builtin_bit_cast(u32, f);
    return (u16)((u + 0x7FFFu + ((u >> 16) & 1u)) >> 16);
}
__device__ __forceinline__ void unpack8(uint4 q, float* f) {
    u32 w[4] = {q.x, q.y, q.z, q.w};
#pragma unroll
    for (int i = 0; i < 4; i++) {
        f[2 * i]     = bf2f((u16)(w[i] & 0xffffu));
        f[2 * i + 1] = bf2f((u16)(w[i] >> 16));
    }
}
__device__ __forceinline__ uint4 pack8(const float* f) {
    uint4 q;
    q.x = (u32)f2bf(f[0]) | ((u32)f2bf(f[1]) << 16);
    q.y = (u32)f2bf(f[2]) | ((u32)f2bf(f[3]) << 16);
    q.z = (u32)f2bf(f[4]) | ((u32)f2bf(f[5]) << 16);
    q.w = (u32)f2bf(f[6]) | ((u32)f2bf(f[7]) << 16);
    return q;
}

// ---------------- fp32 -> bf16 converter (n % 4 == 0) ----------------
__global__ __launch_bounds__(256) void cvt_kernel(
    const float* __restrict__ src, u16* __restrict__ dst, int n4)
{
    int i = blockIdx.x * 256 + threadIdx.x;
    if (i >= n4) return;
    float4 v = ((const float4*)src)[i];
    ushort4 o;
    o.x = f2bf(v.x); o.y = f2bf(v.y); o.z = f2bf(v.z); o.w = f2bf(v.w);
    ((ushort4*)dst)[i] = o;
}

// ---------------- Wdt pad-converter: [1536,48] fp32 -> [1536,64] bf16 (cols 48-63 = 0) ----------------
__global__ __launch_bounds__(256) void cvt_pad_kernel(
    const float* __restrict__ src, u16* __restrict__ dst)
{
    int id = blockIdx.x * 256 + threadIdx.x;   // over 1536*64
    int row = id >> 6, col = id & 63;
    dst[id] = (col < DTRANK) ? f2bf(src[row * DTRANK + col]) : (u16)0;
}

// ---------------- fused residual add + layernorm (fp32 in, fp32 res_out, bf16 u) ----------------
__global__ __launch_bounds__(256) void ln_kernel(
    const float* __restrict__ x, const float* __restrict__ res,
    const float* __restrict__ g, const float* __restrict__ b,
    float* __restrict__ res_out, u16* __restrict__ u)
{
    __shared__ float sbuf[4];
    const int row = blockIdx.x;
    const int tid = threadIdx.x;
    const size_t base = (size_t)row * DMODEL;
    float v[3];
    float s = 0.f;
#pragma unroll
    for (int i = 0; i < 3; i++) {
        int idx = tid + i * 256;
        v[i] = x[base + idx] + res[base + idx];
        res_out[base + idx] = v[i];
        s += v[i];
    }
#pragma unroll
    for (int o = 1; o < 64; o <<= 1) s += __shfl_xor(s, o);
    if ((tid & 63) == 0) sbuf[tid >> 6] = s;
    __syncthreads();
    s = sbuf[0] + sbuf[1] + sbuf[2] + sbuf[3];
    const float mean = s * (1.f / 768.f);
    float var = 0.f;
#pragma unroll
    for (int i = 0; i < 3; i++) { float d = v[i] - mean; var += d * d; }
#pragma unroll
    for (int o = 1; o < 64; o <<= 1) var += __shfl_xor(var, o);
    __syncthreads();
    if ((tid & 63) == 0) sbuf[tid >> 6] = var;
    __syncthreads();
    var = (sbuf[0] + sbuf[1] + sbuf[2] + sbuf[3]) * (1.f / 768.f);
    const float rs = rsqrtf(var + 1e-5f);
#pragma unroll
    for (int i = 0; i < 3; i++) {
        int idx = tid + i * 256;
        u[base + idx] = f2bf((v[i] - mean) * rs * g[idx] + b[idx]);
    }
}

// ---------------- big GEMM: C[M,N] = A[M,K]*B[N,K]^T ----------------
// EPI: 0 = bf16 store, 1 = fp32 store, 2 = +bias, softplus, bf16 store
template<int EPI>
__global__ __launch_bounds__(256) void gemm_bt(
    const u16* __restrict__ A, int lda, const u16* __restrict__ B, int ldb,
    void* __restrict__ Cv, int ldc, int K, const float* __restrict__ bias)
{
    __shared__ uint4 As[512];
    __shared__ uint4 Bs[512];
    const int tid = threadIdx.x;
    const int wid = tid >> 6;
    const int lane = tid & 63;
    const int m0 = blockIdx.y * 128;
    const int n0 = blockIdx.x * 128;
    const int wm = (wid >> 1) * 64;
    const int wn = (wid & 1) * 64;
    f32x4 acc[4][4];
#pragma unroll
    for (int i = 0; i < 4; i++)
#pragma unroll
        for (int j = 0; j < 4; j++) acc[i][j] = (f32x4){0.f, 0.f, 0.f, 0.f};

    const int r0 = tid >> 2;
    const int cq = tid & 3;
    const uint4* pa0 = (const uint4*)(A + (size_t)(m0 + r0) * lda) + cq;
    const uint4* pa1 = (const uint4*)(A + (size_t)(m0 + 64 + r0) * lda) + cq;
    const uint4* pb0 = (const uint4*)(B + (size_t)(n0 + r0) * ldb) + cq;
    const uint4* pb1 = (const uint4*)(B + (size_t)(n0 + 64 + r0) * ldb) + cq;
    const int fr = lane & 15;
    const int kq = lane >> 4;

    for (int k0 = 0; k0 < K; k0 += 32) {
        const int kk = k0 >> 3;
        uint4 a0 = pa0[kk];
        uint4 a1 = pa1[kk];
        uint4 b0 = pb0[kk];
        uint4 b1 = pb1[kk];
        __syncthreads();
        As[r0 * 4 + cq] = a0;
        As[(64 + r0) * 4 + cq] = a1;
        Bs[r0 * 4 + cq] = b0;
        Bs[(64 + r0) * 4 + cq] = b1;
        __syncthreads();
        bf16x8 af[4], bfr[4];
#pragma unroll
        for (int i = 0; i < 4; i++) {
            af[i]  = __builtin_bit_cast(bf16x8, As[(wm + i * 16 + fr) * 4 + kq]);
            bfr[i] = __builtin_bit_cast(bf16x8, Bs[(wn + i * 16 + fr) * 4 + kq]);
        }
#pragma unroll
        for (int i = 0; i < 4; i++)
#pragma unroll
            for (int j = 0; j < 4; j++)
                acc[i][j] = __builtin_amdgcn_mfma_f32_16x16x32_bf16(af[i], bfr[j], acc[i][j], 0, 0, 0);
    }
    const int col = lane & 15;
    const int rb = (lane >> 4) * 4;
#pragma unroll
    for (int i = 0; i < 4; i++)
#pragma unroll
        for (int j = 0; j < 4; j++)
#pragma unroll
            for (int r = 0; r < 4; r++) {
                int m = m0 + wm + i * 16 + rb + r;
                int nn = n0 + wn + j * 16 + col;
                float v = acc[i][j][r];
                if (EPI == 1) {
                    ((float*)Cv)[(size_t)m * ldc + nn] = v;
                } else if (EPI == 2) {
                    v += bias[nn];
                    v = (v > 20.f) ? v : log1pf(__expf(v));
                    ((u16*)Cv)[(size_t)m * ldc + nn] = f2bf(v);
                } else {
                    ((u16*)Cv)[(size_t)m * ldc + nn] = f2bf(v);
                }
            }
}

// ---------------- split-K x_proj: P[ks][M][80] partial = A[M,Kslice]*B[80,Kslice]^T ----------------
__global__ __launch_bounds__(256) void gemm_xproj(
    const u16* __restrict__ A, const u16* __restrict__ B, float* __restrict__ P)
{
    __shared__ uint4 As[256];       // 64 rows x 4 uint4
    __shared__ uint4 Bs[320];       // 80 rows x 4 uint4
    const int tid = threadIdx.x;
    const int wid = tid >> 6;
    const int lane = tid & 63;
    const int m0 = blockIdx.y * 64;
    const int kbase = blockIdx.x * (DINNER / XP_KS);    // 192-wide K slice
    f32x4 acc[5];
#pragma unroll
    for (int j = 0; j < 5; j++) acc[j] = (f32x4){0.f, 0.f, 0.f, 0.f};

    const int ra = tid >> 2;
    const int qa = tid & 3;
    const int fr = lane & 15;
    const int kq = lane >> 4;

    for (int ks = 0; ks < DINNER / XP_KS; ks += 32) {
        const int k0 = kbase + ks;
        uint4 av = *((const uint4*)(A + (size_t)(m0 + ra) * DINNER + k0) + qa);
        uint4 bv0, bv1;
        {
            int rb_ = tid >> 2, qb = tid & 3;
            bv0 = *((const uint4*)(B + (size_t)rb_ * DINNER + k0) + qb);
            int e2 = tid + 256;
            int rb2 = e2 >> 2, qb2 = e2 & 3;
            bv1 = (e2 < 320) ? *((const uint4*)(B + (size_t)rb2 * DINNER + k0) + qb2)
                             : (uint4){0, 0, 0, 0};
        }
        __syncthreads();
        As[ra * 4 + qa] = av;
        Bs[tid] = bv0;
        if (tid < 64) Bs[tid + 256] = bv1;
        __syncthreads();
        bf16x8 af = __builtin_bit_cast(bf16x8, As[(wid * 16 + fr) * 4 + kq]);
#pragma unroll
        for (int j = 0; j < 5; j++) {
            bf16x8 bf = __builtin_bit_cast(bf16x8, Bs[(j * 16 + fr) * 4 + kq]);
            acc[j] = __builtin_amdgcn_mfma_f32_16x16x32_bf16(af, bf, acc[j], 0, 0, 0);
        }
    }
    const int col = lane & 15;
    const int rb = (lane >> 4) * 4;
    float* Pb = P + (size_t)blockIdx.x * M_TOK * 80;
#pragma unroll
    for (int j = 0; j < 5; j++)
#pragma unroll
        for (int r = 0; r < 4; r++) {
            int m = m0 + wid * 16 + rb + r;
            Pb[(size_t)m * 80 + j * 16 + col] = acc[j][r];
        }
}

// reduce XP_KS fp32 partials -> bc_buf (8192x32: cols 48..79) AND padded pjp (8192x64: cols 0..47 + 0-pad)
__global__ __launch_bounds__(256) void xproj_reduce(
    const float* __restrict__ P, u16* __restrict__ bc, u16* __restrict__ pjp)
{
    int i = blockIdx.x * 256 + threadIdx.x;   // over 8192*80
    float s = 0.f;
#pragma unroll
    for (int ks = 0; ks < XP_KS; ks++)
        s += P[(size_t)ks * M_TOK * 80 + i];
    u16 v = f2bf(s);
    int row = i / 80, col = i - row * 80;
    if (col >= DTRANK)
        bc[(size_t)row * 32 + (col - DTRANK)] = v;
    if (col < 64)
        pjp[(size_t)row * 64 + col] = (col < DTRANK) ? v : (u16)0;
}

// ---------------- causal depthwise conv(4) + SiLU ----------------
__global__ __launch_bounds__(256) void conv_silu_kernel(
    const u16* __restrict__ xz, const float* __restrict__ cw, const float* __restrict__ cb,
    u16* __restrict__ xc)
{
    size_t i = (size_t)blockIdx.x * 256 + threadIdx.x;
    if (i >= (size_t)M_TOK * DINNER) return;
    int d = (int)(i % DINNER);
    size_t m = i / DINNER;
    int l = (int)(m & (SEQLEN - 1));
    float acc = cb[d];
#pragma unroll
    for (int k = 0; k < 4; k++) {
        int ls = l - 3 + k;
        if (ls >= 0)
            acc += bf2f(xz[(m - 3 + k) * (2 * DINNER) + d]) * cw[d * 4 + k];
    }
    xc[i] = f2bf(acc / (1.f + __expf(-acc)));
}

// ========== chunked selective scan: lane-per-d, n in registers; B/C from bc_buf (32-wide rows) ==========
__global__ __launch_bounds__(256) void scan_partA(
    const u16* __restrict__ dtp, const u16* __restrict__ xc, const u16* __restrict__ bc,
    const float* __restrict__ Alog,
    float* __restrict__ Sbuf, uint4* __restrict__ Hfin)
{
    const int d = blockIdx.x * 256 + threadIdx.x;
    const int c = blockIdx.y;
    const int b = blockIdx.z;
    float A[16], h[16];
#pragma unroll
    for (int n = 0; n < 16; n++) {
        A[n] = -__expf(Alog[(size_t)d * 16 + n]);
        h[n] = 0.f;
    }
    float S = 0.f;
    const size_t tbase = (size_t)b * SEQLEN + (size_t)c * CLEN;
    for (int t = 0; t < CLEN; t++) {
        const size_t tt = tbase + t;
        float dt = bf2f(dtp[tt * DINNER + d]);
        float x  = bf2f(xc[tt * DINNER + d]);
        const uint4* prow = (const uint4*)(bc + tt * 32);
        float Bv[16];
        unpack8(prow[0], Bv);
        unpack8(prow[1], Bv + 8);
        S += dt;
        float bx = dt * x;
#pragma unroll
        for (int n = 0; n < 16; n++)
            h[n] = fmaf(__expf(dt * A[n]), h[n], bx * Bv[n]);
    }
    const size_t idx = ((size_t)(b * NCHUNK + c) * DINNER + d);
    Sbuf[idx] = S;
    Hfin[idx * 2]     = pack8(h);
    Hfin[idx * 2 + 1] = pack8(h + 8);
}

__global__ __launch_bounds__(256) void scan_partB(
    const float* __restrict__ Sbuf, const uint4* __restrict__ Hfin,
    const float* __restrict__ Alog, uint4* __restrict__ Hin)
{
    const int id = blockIdx.x * 256 + threadIdx.x;
    const int b = id / DINNER;
    const int d = id - b * DINNER;
    float A[16], h[16];
#pragma unroll
    for (int n = 0; n < 16; n++) {
        A[n] = -__expf(Alog[(size_t)d * 16 + n]);
        h[n] = 0.f;
    }
    for (int c = 0; c < NCHUNK; c++) {
        const size_t idx = ((size_t)(b * NCHUNK + c) * DINNER + d);
        Hin[idx * 2]     = pack8(h);
        Hin[idx * 2 + 1] = pack8(h + 8);
        float S = Sbuf[idx];
        float hf[16];
        unpack8(Hfin[idx * 2], hf);
        unpack8(Hfin[idx * 2 + 1], hf + 8);
#pragma unroll
        for (int n = 0; n < 16; n++)
            h[n] = fmaf(__expf(A[n] * S), h[n], hf[n]);
    }
}

__global__ __launch_bounds__(256) void scan_partC(
    const u16* __restrict__ dtp, const u16* __restrict__ xc, const u16* __restrict__ bc,
    u16* xz, const float* __restrict__ Alog, const float* __restrict__ Dp,
    const uint4* __restrict__ Hin)
{
    const int d = blockIdx.x * 256 + threadIdx.x;
    const int c = blockIdx.y;
    const int b = blockIdx.z;
    float A[16], h[16];
#pragma unroll
    for (int n = 0; n < 16; n++)
        A[n] = -__expf(Alog[(size_t)d * 16 + n]);
    {
        const size_t idx = ((size_t)(b * NCHUNK + c) * DINNER + d);
        unpack8(Hin[idx * 2], h);
        unpack8(Hin[idx * 2 + 1], h + 8);
    }
    const float D_d = Dp[d];
    const size_t tbase = (size_t)b * SEQLEN + (size_t)c * CLEN;
    for (int t = 0; t < CLEN; t++) {
        const size_t tt = tbase + t;
        float dt = bf2f(dtp[tt * DINNER + d]);
        float x  = bf2f(xc[tt * DINNER + d]);
        float z  = bf2f(xz[tt * (2 * DINNER) + DINNER + d]);
        const uint4* prow = (const uint4*)(bc + tt * 32);
        float Bv[16], Cv[16];
        unpack8(prow[0], Bv);
        unpack8(prow[1], Bv + 8);
        unpack8(prow[2], Cv);
        unpack8(prow[3], Cv + 8);
        float bx = dt * x;
        float y = 0.f;
#pragma unroll
        for (int n = 0; n < 16; n++) {
            h[n] = fmaf(__expf(dt * A[n]), h[n], bx * Bv[n]);
            y = fmaf(h[n], Cv[n], y);
        }
        float yv = (y + x * D_d) * (z / (1.f + __expf(-z)));
        xz[tt * (2 * DINNER) + d] = f2bf(yv);
    }
}

extern "C" void kernel_launch(void* const* d_in, const int* in_sizes, int n_in,
                              void* d_out, int out_size, void* d_ws, size_t ws_size,
                              hipStream_t stream) {
    (void)in_sizes; (void)n_in; (void)out_size; (void)ws_size;
    const float* x    = (const float*)d_in[0];
    const float* res  = (const float*)d_in[1];
    const float* lng  = (const float*)d_in[2];
    const float* lnb  = (const float*)d_in[3];
    const float* Win  = (const float*)d_in[4];
    const float* cw   = (const float*)d_in[5];
    const float* cb   = (const float*)d_in[6];
    const float* Wxp  = (const float*)d_in[7];
    const float* Wdt  = (const float*)d_in[8];
    const float* bdt  = (const float*)d_in[9];
    const float* Alog = (const float*)d_in[10];
    const float* Dp   = (const float*)d_in[11];
    const float* Wout = (const float*)d_in[12];

    float* out = (float*)d_out;
    float* res_out = out + (size_t)M_TOK * DMODEL;

    // Workspace layout — MUST end <= 122,863,616 B (round-7-proven ws_size bound;
    // exceeding it corrupts the harness's pristine input copies -> post-timing failure)
    char* ws = (char*)d_ws;
    u16* xz_buf = (u16*)(ws);                  //   0 .. 50,331,648
    u16* xc_buf = (u16*)(ws + 50331648);       //  .. 75,497,472
    u16* dt_buf = (u16*)(ws + 75497472);       //  .. 100,663,296
    u16* u_buf  = dt_buf;                      //  (u dead before dt written)
    float* Pbuf = (float*)(ws + 75497472);     //  x_proj partials, 20,971,520 (dead before dt written)
    u16* bc_buf = (u16*)(ws + 100663296);      //  .. 101,187,584 (8192x32 bf16 B/C)
    u16* Wdtp   = (u16*)(ws + 101187584);      //  .. 101,384,192 (1536x64 padded)
    float* Sbuf = (float*)(ws + 101384192);    //  .. 102,170,624
    uint4* Hfin = (uint4*)(ws + 102170624);    //  .. 108,462,080
    uint4* Hin  = (uint4*)(ws + 108462080);    //  .. 114,753,536
    u16* Winb   = (u16*)(ws + 114753536);      //  .. 119,472,128 (dead after in_proj)
    u16* pjp_buf = (u16*)(ws + 114753536);     //  8192x64, reuses Winb slot (written step 4b > read step 2)
    u16* Woutb  = (u16*)(ws + 119472128);      //  .. 121,831,424
    u16* Wxpb   = (u16*)(ws + 121831424);      //  .. 122,077,184  (TOTAL END — safe)

    // 0. convert weights fp32 -> bf16
    cvt_kernel<<<(3072 * 768 / 4 + 255) / 256, 256, 0, stream>>>(Win, Winb, 3072 * 768 / 4);
    cvt_kernel<<<(768 * 1536 / 4 + 255) / 256, 256, 0, stream>>>(Wout, Woutb, 768 * 1536 / 4);
    cvt_kernel<<<(80 * 1536 / 4 + 255) / 256, 256, 0, stream>>>(Wxp, Wxpb, 80 * 1536 / 4);
    cvt_pad_kernel<<<(1536 * 64) / 256, 256, 0, stream>>>(Wdt, Wdtp);
    // 1. res+x (fp32 out), layernorm (bf16 u)
    ln_kernel<<<M_TOK, 256, 0, stream>>>(x, res, lng, lnb, res_out, u_buf);
    // 2. in_proj
    gemm_bt<0><<<dim3(3072 / 128, M_TOK / 128), 256, 0, stream>>>(
        u_buf, DMODEL, Winb, DMODEL, xz_buf, 2 * DINNER, DMODEL, nullptr);
    // 3. conv + silu
    conv_silu_kernel<<<(M_TOK * DINNER) / 256, 256, 0, stream>>>(xz_buf, cw, cb, xc_buf);
    // 4. x_proj: split-K partials + reduce (emits bc_buf and padded pjp)
    gemm_xproj<<<dim3(XP_KS, M_TOK / 64), 256, 0, stream>>>(xc_buf, Wxpb, Pbuf);
    xproj_reduce<<<(M_TOK * 80) / 256, 256, 0, stream>>>(Pbuf, bc_buf, pjp_buf);
    // 5. dt = softplus(pjp @ Wdtp^T + b_dt) via tuned gemm_bt, K=64 padded
    gemm_bt<2><<<dim3(DINNER / 128, M_TOK / 128), 256, 0, stream>>>(
        pjp_buf, 64, Wdtp, 64, dt_buf, DINNER, 64, bdt);
    // 6. chunked selective scan
    scan_partA<<<dim3(DINNER / 256, NCHUNK, 4), 256, 0, stream>>>(
        dt_buf, xc_buf, bc_buf, Alog, Sbuf, Hfin);
    scan_partB<<<(4 * DINNER) / 256, 256, 0, stream>>>(Sbuf, Hfin, Alog, Hin);
    scan_partC<<<dim3(DINNER / 256, NCHUNK, 4), 256, 0, stream>>>(
        dt_buf, xc_buf, bc_buf, xz_buf, Alog, Dp, Hin);
    // 7. out_proj (fp32 out), y strided in xz
    gemm_bt<1><<<dim3(DMODEL / 128, M_TOK / 128), 256, 0, stream>>>(
        xz_buf, 2 * DINNER, Woutb, DINNER, out, DMODEL, DINNER, nullptr);
}